// Round 1
// baseline (23.768 us; speedup 1.0000x reference)
//
#include <hip/hip_runtime.h>
#include <hip/hip_bf16.h>
#include <math.h>

// h[d, l] = 2 * Re( sum_n C[d,n] * exp(dtA[d,n] * l) ),  dtA = (-exp(inv_A_real) + i*A_imag) * dt[d]
//
// Per mode: u_l = Re(C2 * z^l), z = exp(dtA). On the stride-64 lattice
// l = l0 + 64k, u satisfies u_{k+1} = p*u_k + q*u_{k-1} with
//   p = 2*Re(z^64), q = -|z^64|^2.
// 3 VALU ops per (mode, element) in the main loop, zero transcendentals.

constexpr int D_MODEL = 1024;
constexpr int NMODES  = 32;
constexpr int SEQLEN  = 4096;
constexpr int SPLIT   = 2;               // waves per d row
constexpr int LPW     = SEQLEN / SPLIT;  // l-values per wave (2048)
constexpr int ITERS   = LPW / 64;        // 32 iterations, lanes stride 64

__global__ __launch_bounds__(256, 2)
void modal_filter_kernel(const float* __restrict__ log_dt,
                         const float* __restrict__ C_ri,
                         const float* __restrict__ inv_A_real,
                         const float* __restrict__ A_imag,
                         float* __restrict__ out)
{
    const int tid   = blockIdx.x * blockDim.x + threadIdx.x;
    const int wave  = tid >> 6;
    const int lane  = tid & 63;
    const int d     = wave / SPLIT;
    const int split = wave % SPLIT;
    const int base  = split * LPW;
    const float l0f = (float)(base + lane);

    const float dt = __expf(log_dt[d]);

    float uA[NMODES], uB[NMODES], P[NMODES], Q[NMODES];

#pragma unroll
    for (int n = 0; n < NMODES; ++n) {
        const int idx   = d * NMODES + n;
        const float a   = -__expf(inv_A_real[idx]) * dt;
        const float b   = A_imag[idx] * dt;
        const float cr2 = 2.0f * C_ri[2 * idx + 0];
        const float ci2 = 2.0f * C_ri[2 * idx + 1];

        // state at l0 (Re and Im of C2 * z^l0)
        float s, c;
        const float ea = __expf(a * l0f);
        __sincosf(b * l0f, &s, &c);
        const float u0 = ea * (cr2 * c - ci2 * s);
        const float v0 = ea * (cr2 * s + ci2 * c);

        // z^64 (wave-uniform per mode)
        float s64, c64;
        const float e64 = __expf(64.0f * a);
        __sincosf(64.0f * b, &s64, &c64);
        const float x = e64 * c64;
        const float y = e64 * s64;

        uA[n] = u0;
        uB[n] = u0 * x - v0 * y;       // u at l0 + 64 via complex mul (no extra trans)
        P[n]  = 2.0f * x;
        Q[n]  = -(e64 * e64);
    }

    float* outp = out + (size_t)d * SEQLEN + base + lane;

    for (int k = 0; k < ITERS; ++k) {
        // shallow-tree accumulate of the 32 mode states
        float acc0 = 0.0f, acc1 = 0.0f, acc2 = 0.0f, acc3 = 0.0f;
#pragma unroll
        for (int n = 0; n < NMODES; n += 4) {
            acc0 += uA[n + 0];
            acc1 += uA[n + 1];
            acc2 += uA[n + 2];
            acc3 += uA[n + 3];
        }
        outp[k * 64] = (acc0 + acc1) + (acc2 + acc3);   // 64 lanes -> 256B coalesced

        // advance all resonators by one lattice step (stride 64 in l)
#pragma unroll
        for (int n = 0; n < NMODES; ++n) {
            const float t = Q[n] * uA[n];
            uA[n] = uB[n];
            uB[n] = fmaf(P[n], uB[n], t);
        }
    }
}

extern "C" void kernel_launch(void* const* d_in, const int* in_sizes, int n_in,
                              void* d_out, int out_size, void* d_ws, size_t ws_size,
                              hipStream_t stream) {
    const float* log_dt     = (const float*)d_in[0];
    const float* C_ri       = (const float*)d_in[1];
    const float* inv_A_real = (const float*)d_in[2];
    const float* A_imag     = (const float*)d_in[3];
    float* out              = (float*)d_out;

    const int total_threads = D_MODEL * SPLIT * 64;  // one wave per (d, split)
    const int block         = 256;
    const int grid          = total_threads / block; // 512 blocks

    modal_filter_kernel<<<grid, block, 0, stream>>>(log_dt, C_ri, inv_A_real, A_imag, out);
}

// Round 2
// 11.320 us; speedup vs baseline: 2.0998x; 2.0998x over previous
//
#include <hip/hip_runtime.h>
#include <hip/hip_bf16.h>
#include <math.h>

// h[d, l] = 2*Re( sum_n C[d,n] * exp(dtA[d,n] * l) )
// Factor l = i + 64*j, i,j in [0,64):
//   h[d][i+64j] = Re( sum_n S[n][i] * T[n][j] ),
//   S[n][i] = 2*C[d,n] * z_n^i,  T[n][j] = (z_n^64)^j,  z_n = exp(dtA[d,n]).
// Per d this is a complex rank-32 outer product = two f16 MFMA 16x16x32 passes:
//   h_tile = Sr^T*Tr + Si^T*(-Ti), K = 32 = NMODES in one MFMA.
// One wave per d; 16 output tiles of 16x16; fragments generated in-register
// (no LDS). Kernel is output-write-bound (16.8 MB), MFMA work is trivial.

constexpr int D_MODEL = 1024;
constexpr int NMODES  = 32;
constexpr int SEQLEN  = 4096;

typedef _Float16 half8 __attribute__((ext_vector_type(8)));
typedef float    f32x4 __attribute__((ext_vector_type(4)));

__global__ __launch_bounds__(256, 1)
void modal_mfma_kernel(const float* __restrict__ log_dt,
                       const float* __restrict__ C_ri,
                       const float* __restrict__ inv_A_real,
                       const float* __restrict__ A_imag,
                       float* __restrict__ out)
{
    const int wave = threadIdx.x >> 6;          // 4 waves/block, one d each
    const int lane = threadIdx.x & 63;
    const int d    = blockIdx.x * 4 + wave;
    const int g    = lane >> 4;                 // k-group (modes 8g..8g+7)
    const int q    = lane & 15;                 // row (A: m=i-offset) / col (B: n=j-offset)
    const float qf = (float)q;

    const float dt = __expf(log_dt[d]);

    // A-fragments: S[k][i0+q] = C2_k * z_k^(i0+q), i0 = 16*ti
    // B-fragments: T[k][j0+q] = z_k^(64*(j0+q)),   j0 = 16*tj  (imag negated)
    half8 Sr[4], Si[4], Tr[4], Tin[4];

#pragma unroll
    for (int e = 0; e < 8; ++e) {
        const int k   = 8 * g + e;
        const int idx = d * NMODES + k;
        const float a   = -__expf(inv_A_real[idx]) * dt;   // Re(dtA)
        const float b   = A_imag[idx] * dt;                // Im(dtA)
        const float cr2 = 2.0f * C_ri[2 * idx + 0];
        const float ci2 = 2.0f * C_ri[2 * idx + 1];

        // S base: C2 * z^q
        float s, c;
        float ea = __expf(a * qf);
        __sincosf(b * qf, &s, &c);
        float pr = ea * (cr2 * c - ci2 * s);
        float pi = ea * (cr2 * s + ci2 * c);
        // S step: z^16
        float s16, c16;
        float e16 = __expf(16.0f * a);
        __sincosf(16.0f * b, &s16, &c16);
        float xr = e16 * c16, xi = e16 * s16;
        // T base: z^(64q)
        float sq, cq;
        float eq = __expf(64.0f * a * qf);
        __sincosf(64.0f * b * qf, &sq, &cq);
        float tr = eq * cq, ti = eq * sq;
        // T step: z^1024
        float s1k, c1k;
        float e1k = __expf(1024.0f * a);
        __sincosf(1024.0f * b, &s1k, &c1k);
        float yr = e1k * c1k, yi = e1k * s1k;

#pragma unroll
        for (int t = 0; t < 4; ++t) {
            Sr[t][e]  = (_Float16)pr;
            Si[t][e]  = (_Float16)pi;
            Tr[t][e]  = (_Float16)tr;
            Tin[t][e] = (_Float16)(-ti);
            // advance to next tile: S *= z^16, T *= z^1024
            float npr = pr * xr - pi * xi;  pi = pr * xi + pi * xr;  pr = npr;
            float ntr = tr * yr - ti * yi;  ti = tr * yi + ti * yr;  tr = ntr;
        }
    }

    // 16 tiles: acc = Sr^T*Tr + Si^T*(-Ti); store immediately (one tile live).
    // C/D layout (HW-verified): col = lane&15 = n (j-offset),
    //                           row = 4*(lane>>4)+reg = m (i-offset)
    // -> lane's 4 regs are consecutive i -> float4 store, fully coalesced.
    float* od = out + (size_t)d * SEQLEN;
#pragma unroll
    for (int ti = 0; ti < 4; ++ti) {
#pragma unroll
        for (int tj = 0; tj < 4; ++tj) {
            f32x4 acc = {0.f, 0.f, 0.f, 0.f};
            acc = __builtin_amdgcn_mfma_f32_16x16x32_f16(Sr[ti], Tr[tj],  acc, 0, 0, 0);
            acc = __builtin_amdgcn_mfma_f32_16x16x32_f16(Si[ti], Tin[tj], acc, 0, 0, 0);
            const int i = ti * 16 + 4 * g;     // multiple of 4 -> 16B aligned
            const int j = tj * 16 + q;
            *reinterpret_cast<f32x4*>(od + (size_t)j * 64 + i) = acc;
        }
    }
}

extern "C" void kernel_launch(void* const* d_in, const int* in_sizes, int n_in,
                              void* d_out, int out_size, void* d_ws, size_t ws_size,
                              hipStream_t stream) {
    const float* log_dt     = (const float*)d_in[0];
    const float* C_ri       = (const float*)d_in[1];
    const float* inv_A_real = (const float*)d_in[2];
    const float* A_imag     = (const float*)d_in[3];
    float* out              = (float*)d_out;

    // one wave per d: 1024 waves = 256 blocks x 4 waves
    modal_mfma_kernel<<<D_MODEL / 4, 256, 0, stream>>>(log_dt, C_ri, inv_A_real, A_imag, out);
}

// Round 3
// 10.956 us; speedup vs baseline: 2.1695x; 1.0332x over previous
//
#include <hip/hip_runtime.h>
#include <hip/hip_bf16.h>
#include <math.h>

// h[d, l] = 2*Re( sum_n C[d,n] * exp(dtA[d,n] * l) )
// Factor l = i + 16*j, i in [0,16), j in [0,256):
//   h[d][i+16j] = Re( sum_n S[n][i] * T[n][j] ),
//   S[n][i] = 2*C[d,n] * z_n^i          (single 16-wide A fragment)
//   T[n][j] = z_n^(16j)                 (walked 16 columns/tile via *= z^256)
// Two f16 MFMA 16x16x32 per tile (Re = Sr^T*Tr + Si^T*(-Ti)), K=32=NMODES.
// D-tile layout (col=lane&15=j-offset, row=4*(lane>>4)+reg=i) makes every
// wave-store a CONTIGUOUS 1KB f32x4 burst (R2's 64B-scattered partial-line
// stores were the bottleneck). 2 waves per d (2048 waves = 2/SIMD) so setup
// transcendental latency overlaps the store drain.

constexpr int D_MODEL = 1024;
constexpr int NMODES  = 32;
constexpr int SEQLEN  = 4096;
constexpr int WAVES_PER_D = 2;
constexpr int TILES_PER_WAVE = 16 / WAVES_PER_D;   // 8 tiles of 16 j-columns

typedef _Float16 half8 __attribute__((ext_vector_type(8)));
typedef float    f32x4 __attribute__((ext_vector_type(4)));

__global__ __launch_bounds__(256, 2)
void modal_mfma_kernel(const float* __restrict__ log_dt,
                       const float* __restrict__ C_ri,
                       const float* __restrict__ inv_A_real,
                       const float* __restrict__ A_imag,
                       float* __restrict__ out)
{
    const int wave = (blockIdx.x * 256 + (int)threadIdx.x) >> 6;
    const int lane = threadIdx.x & 63;
    const int d    = wave / WAVES_PER_D;
    const int half = wave % WAVES_PER_D;
    const int tj0  = half * TILES_PER_WAVE;
    const int g    = lane >> 4;              // k-group (modes 8g..8g+7)
    const int q    = lane & 15;              // A: row m=i ; B: col n=j-offset
    const float qf = (float)q;

    const float dt = __expf(log_dt[d]);

    half8 Sr, Si;                            // A fragments (i = q)
    float wr[8], wi[8], yr[8], yi[8];        // T walkers + per-tile step z^256

#pragma unroll
    for (int e = 0; e < 8; ++e) {
        const int k   = 8 * g + e;
        const int idx = d * NMODES + k;
        const float a   = -__expf(inv_A_real[idx]) * dt;   // Re(dtA)
        const float b   = A_imag[idx] * dt;                // Im(dtA)
        const float cr2 = 2.0f * C_ri[2 * idx + 0];
        const float ci2 = 2.0f * C_ri[2 * idx + 1];

        // S[k][q] = C2 * z^q
        float s, c;
        const float ea = __expf(a * qf);
        __sincosf(b * qf, &s, &c);
        Sr[e] = (_Float16)(ea * (cr2 * c - ci2 * s));
        Si[e] = (_Float16)(ea * (cr2 * s + ci2 * c));

        // T walker base: z^(16*(16*tj0 + q))
        const float j0 = 16.0f * (16.0f * (float)tj0 + qf);
        float sw, cw;
        const float ew = __expf(a * j0);
        __sincosf(b * j0, &sw, &cw);
        wr[e] = ew * cw;
        wi[e] = ew * sw;

        // per-tile step: z^256
        float sy, cy;
        const float ey = __expf(256.0f * a);
        __sincosf(256.0f * b, &sy, &cy);
        yr[e] = ey * cy;
        yi[e] = ey * sy;
    }

    // store base: floats offset = 16*j + i = 256*tj + 16*q + 4*g (+reg)
    float* od = out + (size_t)d * SEQLEN + 256 * tj0 + 16 * q + 4 * g;

#pragma unroll
    for (int t = 0; t < TILES_PER_WAVE; ++t) {
        half8 Trh, Tih;
#pragma unroll
        for (int e = 0; e < 8; ++e) {
            Trh[e] = (_Float16)wr[e];
            Tih[e] = (_Float16)(-wi[e]);
            const float nr = wr[e] * yr[e] - wi[e] * yi[e];
            wi[e] = wr[e] * yi[e] + wi[e] * yr[e];
            wr[e] = nr;
        }
        f32x4 acc = {0.f, 0.f, 0.f, 0.f};
        acc = __builtin_amdgcn_mfma_f32_16x16x32_f16(Sr, Trh, acc, 0, 0, 0);
        acc = __builtin_amdgcn_mfma_f32_16x16x32_f16(Si, Tih, acc, 0, 0, 0);
        *reinterpret_cast<f32x4*>(od + 256 * t) = acc;   // 64 lanes x 16B = 1KB contiguous
    }
}

extern "C" void kernel_launch(void* const* d_in, const int* in_sizes, int n_in,
                              void* d_out, int out_size, void* d_ws, size_t ws_size,
                              hipStream_t stream) {
    const float* log_dt     = (const float*)d_in[0];
    const float* C_ri       = (const float*)d_in[1];
    const float* inv_A_real = (const float*)d_in[2];
    const float* A_imag     = (const float*)d_in[3];
    float* out              = (float*)d_out;

    // 2048 waves = 2 per d = 512 blocks x 4 waves (2 waves/SIMD chip-wide)
    modal_mfma_kernel<<<D_MODEL * WAVES_PER_D / 4, 256, 0, stream>>>(
        log_dt, C_ri, inv_A_real, A_imag, out);
}